// Round 18
// baseline (272.692 us; speedup 1.0000x reference)
//
#include <hip/hip_runtime.h>
#include <hip/hip_fp16.h>
#include <math.h>

#define NN 100000
#define NE 1000000
#define NCHUNK 160                    // edge chunks for XCD-phased scatter
#define CHUNK (NE/NCHUNK)             // 6250
#define NODE_RANGE (NN/8)             // 12500 nodes per XCD dst-range
#define CAPS 24                       // fixed slots per node (P(deg>24) ~ 5e-5)
#define GXS (NCHUNK*8)                // 1280 scatter blocks

typedef unsigned int   u32;
typedef unsigned short u16;
typedef long long      s64;

__device__ __forceinline__ float lrelu(float x, float sl){ return x >= 0.f ? x : sl*x; }

__device__ __forceinline__ void atomicMaxF(float* a, float v){
    if (v >= 0.f) atomicMax((int*)a, __float_as_int(v));
    else          atomicMin((unsigned int*)a, __float_as_uint(v));
}

// ---------------- merged scatter (blocks < GXS) + prep (blocks >= GXS) ------
template<int DIN, int DINP, int D, bool WRM>
__device__ void coefBody(const float* __restrict__ Wfc, const float* __restrict__ al,
                         const float* __restrict__ ar, const float* __restrict__ We,
                         const float* __restrict__ ae, const float* __restrict__ Wres,
                         const float* __restrict__ bias,
                         float* __restrict__ q, float* __restrict__ r, float* __restrict__ ce,
                         float* __restrict__ wrm, float* __restrict__ bm){
    int t = threadIdx.x;
    for (int i = t; i < 3*DINP; i += 256){
        int hd = i/DINP, k = i - hd*DINP;
        float qa = 0.f, ra = 0.f;
        if (k < DIN){
            for (int d = 0; d < D; ++d){
                float w = Wfc[k*3*D + hd*D + d];
                qa += w*al[hd*D+d];
                ra += w*ar[hd*D+d];
            }
        }
        q[i] = qa; r[i] = ra;
    }
    if (t < 3){
        float c = 0.f;
        for (int d = 0; d < D; ++d) c += We[t*D+d]*ae[t*D+d];
        ce[t] = c;
    }
    if (WRM){
        for (int i = t; i < DIN*D; i += 256){
            int k = i/D, d = i - k*D;
            wrm[i] = (Wres[k*3*D+d] + Wres[k*3*D+D+d] + Wres[k*3*D+2*D+d])*(1.f/3.f);
        }
        for (int i = t; i < D; i += 256)
            bm[i] = (bias[i] + bias[D+i] + bias[2*D+i])*(1.f/3.f);
    }
}

__global__ void __launch_bounds__(256) kScatPrep(
    const int* __restrict__ src, const int* __restrict__ dst,
    const float* __restrict__ ef,
    int* __restrict__ deg, u32* __restrict__ pack,
    int* __restrict__ ovfc, int4* __restrict__ ovf,
    const float* W1, const float* al1, const float* ar1, const float* We1,
    const float* ae1, const float* Wr1, const float* b1,
    const float* W2, const float* al2, const float* ar2, const float* We2,
    const float* ae2, const float* Wr2, const float* b2,
    const float* W3, const float* al3, const float* ar3, const float* We3,
    const float* ae3, const float* Wr3, const float* b3,
    const float* L1a_w, const float* L1a_b,
    float* coef, float* FA, float* FR, float* C0,
    const float* __restrict__ nf, u32* __restrict__ ntab1, float* __restrict__ er3a,
    float* __restrict__ out)
{
    if (blockIdx.x < GXS){
        // ---- XCD-phased scatter, 2 edges/thread, all-NT streams ----
        const int xcd  = blockIdx.x & 7;
        const int base = (blockIdx.x >> 3)*CHUNK;
        for (int e = base + threadIdx.x*2; e < base + CHUNK; e += 512){
            s64 dp = __builtin_nontemporal_load((const s64*)(dst + e));
            int d0 = (int)dp, d1 = (int)(dp >> 32);
            bool m0 = (d0/NODE_RANGE == xcd), m1 = (d1/NODE_RANGE == xcd);
            if (!(m0|m1)) continue;
            s64 sp = __builtin_nontemporal_load((const s64*)(src + e));
            float f0 = __builtin_nontemporal_load(ef + e);
            float f1 = __builtin_nontemporal_load(ef + e + 1);
            int s0 = (int)sp, s1 = (int)(sp >> 32);
            int pos0 = -1, pos1 = -1;
            if (m0) pos0 = atomicAdd(&deg[d0], 1);   // both atomics issue
            if (m1) pos1 = atomicAdd(&deg[d1], 1);   // before either store
            if (m0){
                if (pos0 < CAPS)
                    pack[(size_t)d0*CAPS + pos0] = ((u32)s0 << 15) | (u32)(f0*32767.f + 0.5f);
                else { int o = atomicAdd(ovfc, 1); ovf[o] = make_int4(d0, s0, __float_as_int(f0), 0); }
            }
            if (m1){
                if (pos1 < CAPS)
                    pack[(size_t)d1*CAPS + pos1] = ((u32)s1 << 15) | (u32)(f1*32767.f + 0.5f);
                else { int o = atomicAdd(ovfc, 1); ovf[o] = make_int4(d1, s1, __float_as_int(f1), 0); }
            }
        }
        return;
    }
    const int bid = blockIdx.x - GXS;
    if (bid == 0){
        if (threadIdx.x == 255) out[0] = -INFINITY;
        coefBody<6,8,8,true>(W1, al1, ar1, We1, ae1, Wr1, b1,
            coef+0, coef+24, coef+48, coef+52, coef+100);
    } else if (bid == 1){
        coefBody<8,8,16,true>(W2, al2, ar2, We2, ae2, Wr2, b2,
            coef+108, coef+132, coef+156, coef+160, coef+288);
    } else if (bid == 2){
        coefBody<16,16,32,false>(W3, al3, ar3, We3, ae3, Wr3, b3,
            coef+304, coef+352, coef+400, nullptr, nullptr);
    } else if (bid == 3){
        int t = threadIdx.x;
        for (int i = t; i < 768; i += 256){
            int hd = i >> 8, rem = i & 255;
            int k = rem >> 4, ii = rem & 15;
            float a = 0.f, r = 0.f;
            for (int d = 0; d < 32; ++d){
                float w = L1a_w[d*16 + ii];
                a += W3[k*96 + hd*32 + d]*w;
                r += Wr3[k*96 + hd*32 + d]*w;
            }
            FA[i] = a; FR[i] = r;
        }
        if (t < 48){
            int hd = t >> 4, ii = t & 15;
            float c = L1a_b[ii];
            for (int d = 0; d < 32; ++d) c += b3[hd*32 + d]*L1a_w[d*16 + ii];
            C0[t] = c;
        }
    } else {
        __shared__ float r1s[24];
        int t = threadIdx.x;
        if (t < 24){
            int hd = t >> 3, k = t & 7;
            float ra = 0.f;
            if (k < 6)
                for (int d = 0; d < 8; ++d) ra += W1[k*24 + hd*8 + d]*ar1[hd*8 + d];
            r1s[t] = ra;
        }
        __syncthreads();
        int n = (bid - 4)*256 + t;
        if (n >= NN) return;
        float h[6];
        #pragma unroll
        for (int k = 0; k < 6; ++k) h[k] = nf[(size_t)n*6 + k];
        __half2 p0 = __floats2half2_rn(h[0], h[1]);
        __half2 p1 = __floats2half2_rn(h[2], h[3]);
        __half2 p2 = __floats2half2_rn(h[4], h[5]);
        __half2 p3 = __floats2half2_rn(0.f, 0.f);
        uint4 row;
        row.x = *(u32*)&p0; row.y = *(u32*)&p1; row.z = *(u32*)&p2; row.w = *(u32*)&p3;
        *(uint4*)(ntab1 + (size_t)n*4) = row;
        #pragma unroll
        for (int hd = 0; hd < 3; ++hd){
            float er = 0.f;
            #pragma unroll
            for (int k = 0; k < 6; ++k) er += r1s[hd*8+k]*h[k];
            er3a[(size_t)n*3+hd] = er;
        }
    }
}

// ---------------- fused layer: channel-split quad per node ----------------
// AGG (layer 3): finalize fused in-kernel -- lane's 4-channel head slices feed
// the folded MLP head (FA/FR), quad shfl reduce, block max, atomicMaxF.
template<int DINP, int DINR, int D, bool AGG>
__global__ void __launch_bounds__(256) kNode(
    const int* __restrict__ deg, const u32* __restrict__ pack,
    const int* __restrict__ ovfc, const int4* __restrict__ ovf,
    const u32* __restrict__ ntab,
    const float* __restrict__ er3, const float* __restrict__ qc,
    const float* __restrict__ cep, const float* __restrict__ hres,
    const float* __restrict__ Wfc, const float* __restrict__ Wr2,  // Wrm (non-AGG)
    const float* __restrict__ b2,                                  // bm  (non-AGG)
    float* __restrict__ hmean_o, u32* __restrict__ ntab_next,
    float* __restrict__ er3_next, const float* __restrict__ rnext,
    const float* __restrict__ FAg, const float* __restrict__ FRg,
    const float* __restrict__ C0g,
    const float* __restrict__ L1b_w, const float* __restrict__ L1b_b,
    const float* __restrict__ L1c_w, const float* __restrict__ L1c_b,
    const float* __restrict__ L2_w, const float* __restrict__ L2_b,
    float* __restrict__ out)
{
    constexpr int KS   = DINP/4;     // channels per lane (2 or 4)
    constexpr int ROWU = DINP/2;     // u32 per ntab row (4 or 8)
    constexpr int D4   = D/4;        // out dims per lane (non-AGG)
    const int tid  = threadIdx.x;
    const int lid  = tid & 63;
    const int lane = tid & 3;
    const int n    = (blockIdx.x*256 + tid) >> 2;
    const bool alive = n < NN;

    int dg = 0;
    float e0 = 0.f, e1 = 0.f, e2 = 0.f;
    if (alive){
        dg = deg[n]; if (dg > CAPS) dg = CAPS;
        e0 = er3[(size_t)n*3+0]; e1 = er3[(size_t)n*3+1]; e2 = er3[(size_t)n*3+2];
    }
    const float c0 = cep[0], c1 = cep[1], c2 = cep[2];
    float q[3*KS];
    #pragma unroll
    for (int hd = 0; hd < 3; ++hd)
        #pragma unroll
        for (int ks = 0; ks < KS; ++ks)
            q[hd*KS+ks] = qc[hd*DINP + lane*KS + ks];

    float acc[3*KS];
    #pragma unroll
    for (int v = 0; v < 3*KS; ++v) acc[v] = 0.f;
    float s0 = 0.f, s1 = 0.f, s2 = 0.f;

    auto rowLoad = [&](int sv, u32& w0, u32& w1){
        const u32* rp = ntab + (size_t)sv*ROWU + lane*(KS/2);
        if constexpr (KS == 2){ w0 = rp[0]; w1 = 0u; }
        else { uint2 t2 = *(const uint2*)rp; w0 = t2.x; w1 = t2.y; }
    };
    auto edgeCompute = [&](float fv, u32 w0, u32 w1){
        float hv[KS];
        float2 f = __half22float2(*(__half2*)&w0);
        hv[0] = f.x; hv[1] = f.y;
        if constexpr (KS == 4){
            f = __half22float2(*(__half2*)&w1);
            hv[2] = f.x; hv[3] = f.y;
        }
        float l0 = 0.f, l1 = 0.f, l2 = 0.f;
        #pragma unroll
        for (int ks = 0; ks < KS; ++ks){
            l0 += q[ks]*hv[ks]; l1 += q[KS+ks]*hv[ks]; l2 += q[2*KS+ks]*hv[ks];
        }
        l0 += __shfl_xor(l0,1); l0 += __shfl_xor(l0,2);
        l1 += __shfl_xor(l1,1); l1 += __shfl_xor(l1,2);
        l2 += __shfl_xor(l2,1); l2 += __shfl_xor(l2,2);
        float x0 = __expf(lrelu(l0 + e0 + c0*fv, 0.2f));
        float x1 = __expf(lrelu(l1 + e1 + c1*fv, 0.2f));
        float x2 = __expf(lrelu(l2 + e2 + c2*fv, 0.2f));
        s0 += x0; s1 += x1; s2 += x2;
        #pragma unroll
        for (int ks = 0; ks < KS; ++ks){
            acc[ks]      += x0*hv[ks];
            acc[KS+ks]   += x1*hv[ks];
            acc[2*KS+ks] += x2*hv[ks];
        }
    };

    int p = n*CAPS;
    const int re = p + dg;
    while (p + 1 < re){
        u32 ra = pack[p], rb = pack[p+1];
        u32 a0, a1, b0, b1;
        rowLoad((int)(ra >> 15), a0, a1);
        rowLoad((int)(rb >> 15), b0, b1);
        edgeCompute((float)(ra & 0x7fffu)*(1.f/32767.f), a0, a1);
        edgeCompute((float)(rb & 0x7fffu)*(1.f/32767.f), b0, b1);
        p += 2;
    }
    if (p < re){
        u32 ra = pack[p];
        u32 a0, a1;
        rowLoad((int)(ra >> 15), a0, a1);
        edgeCompute((float)(ra & 0x7fffu)*(1.f/32767.f), a0, a1);
    }

    // overflow edges (statistically ~a handful)
    int nov = ovfc[0];
    for (int i = 0; i < nov; ++i){
        int4 o = ovf[i];
        if (alive && o.x == n){
            u32 a0, a1;
            rowLoad(o.y, a0, a1);
            edgeCompute(__int_as_float(o.z), a0, a1);
        }
    }

    float i0 = s0 > 0.f ? 1.f/s0 : 0.f;
    float i1 = s1 > 0.f ? 1.f/s1 : 0.f;
    float i2 = s2 > 0.f ? 1.f/s2 : 0.f;
    if constexpr (!AGG){ i0 *= (1.f/3.f); i1 *= (1.f/3.f); i2 *= (1.f/3.f); }
    #pragma unroll
    for (int ks = 0; ks < KS; ++ks){
        acc[ks] *= i0; acc[KS+ks] *= i1; acc[2*KS+ks] *= i2;
    }

    if constexpr (AGG){
        // ---- fused finalize + folded MLP head + global max ----
        float hrl[KS];
        #pragma unroll
        for (int ks = 0; ks < KS; ++ks)
            hrl[ks] = alive ? hres[(size_t)n*DINR + lane*KS + ks] : 0.f;
        float y = 0.f;
        #pragma unroll
        for (int hd = 0; hd < 3; ++hd){
            float x1[16];
            #pragma unroll
            for (int i = 0; i < 16; ++i) x1[i] = 0.f;
            #pragma unroll
            for (int ks = 0; ks < KS; ++ks){
                const float a = acc[hd*KS+ks];
                const float h = hrl[ks];
                const float4* fap = (const float4*)(FAg + hd*256 + (lane*KS+ks)*16);
                const float4* frp = (const float4*)(FRg + hd*256 + (lane*KS+ks)*16);
                #pragma unroll
                for (int w = 0; w < 4; ++w){
                    float4 fa4 = fap[w], fr4 = frp[w];
                    x1[4*w+0] += a*fa4.x + h*fr4.x;
                    x1[4*w+1] += a*fa4.y + h*fr4.y;
                    x1[4*w+2] += a*fa4.z + h*fr4.z;
                    x1[4*w+3] += a*fa4.w + h*fr4.w;
                }
            }
            #pragma unroll
            for (int i = 0; i < 16; ++i){
                x1[i] += __shfl_xor(x1[i], 1);
                x1[i] += __shfl_xor(x1[i], 2);
                x1[i] = lrelu(x1[i] + C0g[hd*16 + i], 0.01f);
            }
            float x2[4];
            #pragma unroll
            for (int ii = 0; ii < 4; ++ii){
                float a = L1b_b[ii];
                #pragma unroll
                for (int i = 0; i < 16; ++i) a += x1[i]*L1b_w[i*4+ii];
                x2[ii] = lrelu(a, 0.01f);
            }
            float v = L1c_b[0];
            #pragma unroll
            for (int ii = 0; ii < 4; ++ii) v += x2[ii]*L1c_w[ii];
            y += v*L2_w[hd];
        }
        float ymax = alive ? (y + L2_b[0]) : -INFINITY;
        __shared__ float red[256];
        red[tid] = ymax;
        __syncthreads();
        for (int o = 128; o > 0; o >>= 1){
            if (tid < o) red[tid] = fmaxf(red[tid], red[tid+o]);
            __syncthreads();
        }
        if (tid == 0) atomicMaxF(out, red[0]);
        return;
    } else {
        float hsl[KS];
        #pragma unroll
        for (int ks = 0; ks < KS; ++ks){
            int k = lane*KS + ks;
            hsl[ks] = (alive && k < DINR) ? hres[(size_t)n*DINR + k] : 0.f;
        }
        float hm[D4];
        #pragma unroll
        for (int i = 0; i < D4; ++i) hm[i] = b2[lane*D4 + i];
        #pragma unroll
        for (int r = 0; r < 4; ++r){
            int sl = (lid & ~3) | ((lid + r) & 3);
            int kb = ((lane + r) & 3)*KS;
            float as[3*KS], hs[KS];
            #pragma unroll
            for (int v = 0; v < 3*KS; ++v) as[v] = __shfl(acc[v], sl);
            #pragma unroll
            for (int v = 0; v < KS; ++v) hs[v] = __shfl(hsl[v], sl);
            #pragma unroll
            for (int ks = 0; ks < KS; ++ks){
                int k = kb + ks;
                if (DINP == DINR || k < DINR){
                    #pragma unroll
                    for (int i = 0; i < D4; ++i){
                        int d = lane*D4 + i;
                        hm[i] += as[ks]     *Wfc[k*3*D + d]
                               + as[KS+ks]  *Wfc[k*3*D + D + d]
                               + as[2*KS+ks]*Wfc[k*3*D + 2*D + d]
                               + hs[ks]     *Wr2[k*D + d];
                    }
                }
            }
        }
        if (alive){
            #pragma unroll
            for (int i = 0; i < D4; ++i)
                hmean_o[(size_t)n*D + lane*D4 + i] = hm[i];
            #pragma unroll
            for (int w = 0; w < D4/2; ++w){
                __half2 hh = __floats2half2_rn(hm[2*w], hm[2*w+1]);
                ntab_next[(size_t)n*(D/2) + lane*(D4/2) + w] = *(u32*)&hh;
            }
        }
        float p0 = 0.f, p1 = 0.f, p2 = 0.f;
        #pragma unroll
        for (int i = 0; i < D4; ++i){
            int d = lane*D4 + i;
            p0 += rnext[0*D + d]*hm[i];
            p1 += rnext[1*D + d]*hm[i];
            p2 += rnext[2*D + d]*hm[i];
        }
        p0 += __shfl_xor(p0,1); p0 += __shfl_xor(p0,2);
        p1 += __shfl_xor(p1,1); p1 += __shfl_xor(p1,2);
        p2 += __shfl_xor(p2,1); p2 += __shfl_xor(p2,2);
        if (alive && lane < 3){
            float v = (lane == 0) ? p0 : ((lane == 1) ? p1 : p2);
            er3_next[(size_t)n*3 + lane] = v;
        }
    }
}

extern "C" void kernel_launch(void* const* d_in, const int* in_sizes, int n_in,
                              void* d_out, int out_size, void* d_ws, size_t ws_size,
                              hipStream_t stream) {
    const float* nf  = (const float*)d_in[0];
    const float* ef  = (const float*)d_in[1];
    const float* W1  = (const float*)d_in[2];
    const float* We1 = (const float*)d_in[3];
    const float* al1 = (const float*)d_in[4];
    const float* ar1 = (const float*)d_in[5];
    const float* ae1 = (const float*)d_in[6];
    const float* Wr1 = (const float*)d_in[7];
    const float* b1  = (const float*)d_in[8];
    const float* W2  = (const float*)d_in[9];
    const float* We2 = (const float*)d_in[10];
    const float* al2 = (const float*)d_in[11];
    const float* ar2 = (const float*)d_in[12];
    const float* ae2 = (const float*)d_in[13];
    const float* Wr2 = (const float*)d_in[14];
    const float* b2  = (const float*)d_in[15];
    const float* W3  = (const float*)d_in[16];
    const float* We3 = (const float*)d_in[17];
    const float* al3 = (const float*)d_in[18];
    const float* ar3 = (const float*)d_in[19];
    const float* ae3 = (const float*)d_in[20];
    const float* Wr3 = (const float*)d_in[21];
    const float* b3  = (const float*)d_in[22];
    const float* L1a_w = (const float*)d_in[23];
    const float* L1a_b = (const float*)d_in[24];
    const float* L1b_w = (const float*)d_in[25];
    const float* L1b_b = (const float*)d_in[26];
    const float* L1c_w = (const float*)d_in[27];
    const float* L1c_b = (const float*)d_in[28];
    const float* L2_w  = (const float*)d_in[29];
    const float* L2_b  = (const float*)d_in[30];
    const int* src = (const int*)d_in[31];
    const int* dst = (const int*)d_in[32];
    float* out = (float*)d_out;

    // ---- workspace layout ----
    float* ws = (float*)d_ws;
    u32* ntab1 = (u32*)ws;                       // [N,4] u32 (8 halves)
    u32* ntab2 = ntab1 + (size_t)NN*4;           // [N,4]
    u32* ntab3 = ntab2 + (size_t)NN*4;           // [N,8]
    float* f   = (float*)(ntab3 + (size_t)NN*8);
    float* hm2  = f;  f += (size_t)NN*8;         // layer-2 residual input f32
    float* hm3  = f;  f += (size_t)NN*16;        // layer-3 residual input f32
    float* er3a = f;  f += (size_t)NN*3;
    float* er3b = f;  f += (size_t)NN*3;
    float* coef = f;  f += 512;
    float* FAb = f;  f += 768;
    float* FRb = f;  f += 768;
    float* C0b = f;  f += 64;
    int* deg  = (int*)f;                         // [N] (+1: ovfc)
    int* ovfc = deg + NN;                        // [1]
    int4* ovf = (int4*)(ovfc + 4);               // [4096]
    u32* pack = (u32*)(ovf + 4096);              // [N*CAPS] u32 records

    const int gSP = GXS + 4 + (NN + 255)/256;    // scatter(1280) + coef(4) + prep1(391)
    const int gT  = (NN*4 + 255)/256;            // 4 lanes per node -> 1563

    // ---- init via DMA memset (deg + ovfc) ----
    hipMemsetAsync(deg, 0, (NN + 4)*sizeof(int), stream);

    // ---- merged scatter + coefficients + layer-1 node table + out init ----
    kScatPrep<<<gSP,256,0,stream>>>(src, dst, ef, deg, pack, ovfc, ovf,
                                    W1, al1, ar1, We1, ae1, Wr1, b1,
                                    W2, al2, ar2, We2, ae2, Wr2, b2,
                                    W3, al3, ar3, We3, ae3, Wr3, b3,
                                    L1a_w, L1a_b, coef, FAb, FRb, C0b,
                                    nf, ntab1, er3a, out);

    // ---- Layer 1: DINP=8(pad 6), DINR=6, D=8 ----
    kNode<8,6,8,false><<<gT,256,0,stream>>>(deg, pack, ovfc, ovf, ntab1, er3a,
        coef+0, coef+48, nf, W1, coef+52, coef+100,
        hm2, ntab2, er3b, coef+132,
        nullptr,nullptr,nullptr,nullptr,nullptr,nullptr,nullptr,nullptr,nullptr, nullptr);

    // ---- Layer 2: DINP=8, DINR=8, D=16 ----
    kNode<8,8,16,false><<<gT,256,0,stream>>>(deg, pack, ovfc, ovf, ntab2, er3b,
        coef+108, coef+156, hm2, W2, coef+160, coef+288,
        hm3, ntab3, er3a, coef+352,
        nullptr,nullptr,nullptr,nullptr,nullptr,nullptr,nullptr,nullptr,nullptr, nullptr);

    // ---- Layer 3 (AGG): DINP=16, DINR=16, D=32 + fused folded head + max ----
    kNode<16,16,32,true><<<gT,256,0,stream>>>(deg, pack, ovfc, ovf, ntab3, er3a,
        coef+304, coef+400, hm3, nullptr, nullptr, nullptr,
        nullptr, nullptr, nullptr, nullptr,
        FAb, FRb, C0b, L1b_w, L1b_b, L1c_w, L1c_b, L2_w, L2_b, out);
}

// Round 19
// 172.426 us; speedup vs baseline: 1.5815x; 1.5815x over previous
//
#include <hip/hip_runtime.h>
#include <hip/hip_fp16.h>
#include <math.h>

#define NN 100000
#define NE 1000000
#define NCHUNK 160                    // edge chunks for XCD-phased scatter
#define CHUNK (NE/NCHUNK)             // 6250
#define NODE_RANGE (NN/8)             // 12500 nodes per XCD dst-range
#define CAPS 24                       // fixed slots per node (P(deg>24) ~ 5e-5)
#define GXS (NCHUNK*8)                // 1280 scatter blocks

typedef unsigned int   u32;
typedef unsigned short u16;
typedef long long      s64;

__device__ __forceinline__ float lrelu(float x, float sl){ return x >= 0.f ? x : sl*x; }

__device__ __forceinline__ void atomicMaxF(float* a, float v){
    if (v >= 0.f) atomicMax((int*)a, __float_as_int(v));
    else          atomicMin((unsigned int*)a, __float_as_uint(v));
}

// ---------------- merged scatter (blocks < GXS) + prep (blocks >= GXS) ------
template<int DIN, int DINP, int D, bool WRM>
__device__ void coefBody(const float* __restrict__ Wfc, const float* __restrict__ al,
                         const float* __restrict__ ar, const float* __restrict__ We,
                         const float* __restrict__ ae, const float* __restrict__ Wres,
                         const float* __restrict__ bias,
                         float* __restrict__ q, float* __restrict__ r, float* __restrict__ ce,
                         float* __restrict__ wrm, float* __restrict__ bm){
    int t = threadIdx.x;
    for (int i = t; i < 3*DINP; i += 256){
        int hd = i/DINP, k = i - hd*DINP;
        float qa = 0.f, ra = 0.f;
        if (k < DIN){
            for (int d = 0; d < D; ++d){
                float w = Wfc[k*3*D + hd*D + d];
                qa += w*al[hd*D+d];
                ra += w*ar[hd*D+d];
            }
        }
        q[i] = qa; r[i] = ra;
    }
    if (t < 3){
        float c = 0.f;
        for (int d = 0; d < D; ++d) c += We[t*D+d]*ae[t*D+d];
        ce[t] = c;
    }
    if (WRM){
        for (int i = t; i < DIN*D; i += 256){
            int k = i/D, d = i - k*D;
            wrm[i] = (Wres[k*3*D+d] + Wres[k*3*D+D+d] + Wres[k*3*D+2*D+d])*(1.f/3.f);
        }
        for (int i = t; i < D; i += 256)
            bm[i] = (bias[i] + bias[D+i] + bias[2*D+i])*(1.f/3.f);
    }
}

__global__ void __launch_bounds__(256) kScatPrep(
    const int* __restrict__ src, const int* __restrict__ dst,
    const float* __restrict__ ef,
    int* __restrict__ deg, u32* __restrict__ pack,
    int* __restrict__ ovfc, int4* __restrict__ ovf,
    const float* W1, const float* al1, const float* ar1, const float* We1,
    const float* ae1, const float* Wr1, const float* b1,
    const float* W2, const float* al2, const float* ar2, const float* We2,
    const float* ae2, const float* Wr2, const float* b2,
    const float* W3, const float* al3, const float* ar3, const float* We3,
    const float* ae3, const float* Wr3, const float* b3,
    const float* L1a_w, const float* L1a_b,
    float* coef, float* FA, float* FR, float* C0,
    const float* __restrict__ nf, u32* __restrict__ ntab1, float* __restrict__ er3a,
    float* __restrict__ out)
{
    if (blockIdx.x < GXS){
        // ---- XCD-phased scatter, 2 edges/thread, all-NT streams ----
        const int xcd  = blockIdx.x & 7;
        const int base = (blockIdx.x >> 3)*CHUNK;
        for (int e = base + threadIdx.x*2; e < base + CHUNK; e += 512){
            s64 dp = __builtin_nontemporal_load((const s64*)(dst + e));
            int d0 = (int)dp, d1 = (int)(dp >> 32);
            bool m0 = (d0/NODE_RANGE == xcd), m1 = (d1/NODE_RANGE == xcd);
            if (!(m0|m1)) continue;
            s64 sp = __builtin_nontemporal_load((const s64*)(src + e));
            float f0 = __builtin_nontemporal_load(ef + e);
            float f1 = __builtin_nontemporal_load(ef + e + 1);
            int s0 = (int)sp, s1 = (int)(sp >> 32);
            int pos0 = -1, pos1 = -1;
            if (m0) pos0 = atomicAdd(&deg[d0], 1);   // both atomics issue
            if (m1) pos1 = atomicAdd(&deg[d1], 1);   // before either store
            if (m0){
                if (pos0 < CAPS)
                    pack[(size_t)d0*CAPS + pos0] = ((u32)s0 << 15) | (u32)(f0*32767.f + 0.5f);
                else { int o = atomicAdd(ovfc, 1); ovf[o] = make_int4(d0, s0, __float_as_int(f0), 0); }
            }
            if (m1){
                if (pos1 < CAPS)
                    pack[(size_t)d1*CAPS + pos1] = ((u32)s1 << 15) | (u32)(f1*32767.f + 0.5f);
                else { int o = atomicAdd(ovfc, 1); ovf[o] = make_int4(d1, s1, __float_as_int(f1), 0); }
            }
        }
        return;
    }
    const int bid = blockIdx.x - GXS;
    if (bid == 0){
        if (threadIdx.x == 255) out[0] = -INFINITY;
        coefBody<6,8,8,true>(W1, al1, ar1, We1, ae1, Wr1, b1,
            coef+0, coef+24, coef+48, coef+52, coef+100);
    } else if (bid == 1){
        coefBody<8,8,16,true>(W2, al2, ar2, We2, ae2, Wr2, b2,
            coef+108, coef+132, coef+156, coef+160, coef+288);
    } else if (bid == 2){
        coefBody<16,16,32,false>(W3, al3, ar3, We3, ae3, Wr3, b3,
            coef+304, coef+352, coef+400, nullptr, nullptr);
    } else if (bid == 3){
        int t = threadIdx.x;
        for (int i = t; i < 768; i += 256){
            int hd = i >> 8, rem = i & 255;
            int k = rem >> 4, ii = rem & 15;
            float a = 0.f, r = 0.f;
            for (int d = 0; d < 32; ++d){
                float w = L1a_w[d*16 + ii];
                a += W3[k*96 + hd*32 + d]*w;
                r += Wr3[k*96 + hd*32 + d]*w;
            }
            FA[i] = a; FR[i] = r;
        }
        if (t < 48){
            int hd = t >> 4, ii = t & 15;
            float c = L1a_b[ii];
            for (int d = 0; d < 32; ++d) c += b3[hd*32 + d]*L1a_w[d*16 + ii];
            C0[t] = c;
        }
    } else {
        __shared__ float r1s[24];
        int t = threadIdx.x;
        if (t < 24){
            int hd = t >> 3, k = t & 7;
            float ra = 0.f;
            if (k < 6)
                for (int d = 0; d < 8; ++d) ra += W1[k*24 + hd*8 + d]*ar1[hd*8 + d];
            r1s[t] = ra;
        }
        __syncthreads();
        int n = (bid - 4)*256 + t;
        if (n >= NN) return;
        float h[6];
        #pragma unroll
        for (int k = 0; k < 6; ++k) h[k] = nf[(size_t)n*6 + k];
        __half2 p0 = __floats2half2_rn(h[0], h[1]);
        __half2 p1 = __floats2half2_rn(h[2], h[3]);
        __half2 p2 = __floats2half2_rn(h[4], h[5]);
        __half2 p3 = __floats2half2_rn(0.f, 0.f);
        uint4 row;
        row.x = *(u32*)&p0; row.y = *(u32*)&p1; row.z = *(u32*)&p2; row.w = *(u32*)&p3;
        *(uint4*)(ntab1 + (size_t)n*4) = row;
        #pragma unroll
        for (int hd = 0; hd < 3; ++hd){
            float er = 0.f;
            #pragma unroll
            for (int k = 0; k < 6; ++k) er += r1s[hd*8+k]*h[k];
            er3a[(size_t)n*3+hd] = er;
        }
    }
}

// ---------------- fused layer: channel-split quad per node ----------------
template<int DINP, int DINR, int D, bool AGG>
__global__ void __launch_bounds__(256) kNode(
    const int* __restrict__ deg, const u32* __restrict__ pack,
    const int* __restrict__ ovfc, const int4* __restrict__ ovf,
    const u32* __restrict__ ntab,
    const float* __restrict__ er3, const float* __restrict__ qc,
    const float* __restrict__ cep, const float* __restrict__ hres,
    const float* __restrict__ Wfc, const float* __restrict__ Wr2,  // Wrm (non-AGG)
    const float* __restrict__ b2,                                  // bm  (non-AGG)
    float* __restrict__ hmean_o, u32* __restrict__ ntab_next,
    float* __restrict__ er3_next, const float* __restrict__ rnext,
    float* __restrict__ agg_o)
{
    constexpr int KS   = DINP/4;     // channels per lane (2 or 4)
    constexpr int ROWU = DINP/2;     // u32 per ntab row (4 or 8)
    constexpr int D4   = D/4;        // out dims per lane (non-AGG)
    const int tid  = threadIdx.x;
    const int lid  = tid & 63;
    const int lane = tid & 3;
    const int n    = (blockIdx.x*256 + tid) >> 2;
    const bool alive = n < NN;

    int dg = 0;
    float e0 = 0.f, e1 = 0.f, e2 = 0.f;
    if (alive){
        dg = deg[n]; if (dg > CAPS) dg = CAPS;
        e0 = er3[(size_t)n*3+0]; e1 = er3[(size_t)n*3+1]; e2 = er3[(size_t)n*3+2];
    }
    const float c0 = cep[0], c1 = cep[1], c2 = cep[2];
    float q[3*KS];
    #pragma unroll
    for (int hd = 0; hd < 3; ++hd)
        #pragma unroll
        for (int ks = 0; ks < KS; ++ks)
            q[hd*KS+ks] = qc[hd*DINP + lane*KS + ks];

    float acc[3*KS];
    #pragma unroll
    for (int v = 0; v < 3*KS; ++v) acc[v] = 0.f;
    float s0 = 0.f, s1 = 0.f, s2 = 0.f;

    auto rowLoad = [&](int sv, u32& w0, u32& w1){
        const u32* rp = ntab + (size_t)sv*ROWU + lane*(KS/2);
        if constexpr (KS == 2){ w0 = rp[0]; w1 = 0u; }
        else { uint2 t2 = *(const uint2*)rp; w0 = t2.x; w1 = t2.y; }
    };
    auto edgeCompute = [&](float fv, u32 w0, u32 w1){
        float hv[KS];
        float2 f = __half22float2(*(__half2*)&w0);
        hv[0] = f.x; hv[1] = f.y;
        if constexpr (KS == 4){
            f = __half22float2(*(__half2*)&w1);
            hv[2] = f.x; hv[3] = f.y;
        }
        float l0 = 0.f, l1 = 0.f, l2 = 0.f;
        #pragma unroll
        for (int ks = 0; ks < KS; ++ks){
            l0 += q[ks]*hv[ks]; l1 += q[KS+ks]*hv[ks]; l2 += q[2*KS+ks]*hv[ks];
        }
        l0 += __shfl_xor(l0,1); l0 += __shfl_xor(l0,2);
        l1 += __shfl_xor(l1,1); l1 += __shfl_xor(l1,2);
        l2 += __shfl_xor(l2,1); l2 += __shfl_xor(l2,2);
        float x0 = __expf(lrelu(l0 + e0 + c0*fv, 0.2f));
        float x1 = __expf(lrelu(l1 + e1 + c1*fv, 0.2f));
        float x2 = __expf(lrelu(l2 + e2 + c2*fv, 0.2f));
        s0 += x0; s1 += x1; s2 += x2;
        #pragma unroll
        for (int ks = 0; ks < KS; ++ks){
            acc[ks]      += x0*hv[ks];
            acc[KS+ks]   += x1*hv[ks];
            acc[2*KS+ks] += x2*hv[ks];
        }
    };

    int p = n*CAPS;
    const int re = p + dg;
    while (p + 1 < re){
        u32 ra = pack[p], rb = pack[p+1];
        u32 a0, a1, b0, b1;
        rowLoad((int)(ra >> 15), a0, a1);
        rowLoad((int)(rb >> 15), b0, b1);
        edgeCompute((float)(ra & 0x7fffu)*(1.f/32767.f), a0, a1);
        edgeCompute((float)(rb & 0x7fffu)*(1.f/32767.f), b0, b1);
        p += 2;
    }
    if (p < re){
        u32 ra = pack[p];
        u32 a0, a1;
        rowLoad((int)(ra >> 15), a0, a1);
        edgeCompute((float)(ra & 0x7fffu)*(1.f/32767.f), a0, a1);
    }

    // overflow edges (statistically ~a handful)
    int nov = ovfc[0];
    for (int i = 0; i < nov; ++i){
        int4 o = ovf[i];
        if (alive && o.x == n){
            u32 a0, a1;
            rowLoad(o.y, a0, a1);
            edgeCompute(__int_as_float(o.z), a0, a1);
        }
    }

    float i0 = s0 > 0.f ? 1.f/s0 : 0.f;
    float i1 = s1 > 0.f ? 1.f/s1 : 0.f;
    float i2 = s2 > 0.f ? 1.f/s2 : 0.f;
    if constexpr (!AGG){ i0 *= (1.f/3.f); i1 *= (1.f/3.f); i2 *= (1.f/3.f); }
    #pragma unroll
    for (int ks = 0; ks < KS; ++ks){
        acc[ks] *= i0; acc[KS+ks] *= i1; acc[2*KS+ks] *= i2;
    }

    if constexpr (AGG){
        if (alive){
            #pragma unroll
            for (int hd = 0; hd < 3; ++hd){
                float4 v = make_float4(acc[hd*KS+0], acc[hd*KS+1], acc[hd*KS+2], acc[hd*KS+3]);
                *(float4*)(agg_o + (size_t)n*48 + hd*16 + lane*4) = v;
            }
        }
        return;
    } else {
        float hsl[KS];
        #pragma unroll
        for (int ks = 0; ks < KS; ++ks){
            int k = lane*KS + ks;
            hsl[ks] = (alive && k < DINR) ? hres[(size_t)n*DINR + k] : 0.f;
        }
        float hm[D4];
        #pragma unroll
        for (int i = 0; i < D4; ++i) hm[i] = b2[lane*D4 + i];
        #pragma unroll
        for (int r = 0; r < 4; ++r){
            int sl = (lid & ~3) | ((lid + r) & 3);
            int kb = ((lane + r) & 3)*KS;
            float as[3*KS], hs[KS];
            #pragma unroll
            for (int v = 0; v < 3*KS; ++v) as[v] = __shfl(acc[v], sl);
            #pragma unroll
            for (int v = 0; v < KS; ++v) hs[v] = __shfl(hsl[v], sl);
            #pragma unroll
            for (int ks = 0; ks < KS; ++ks){
                int k = kb + ks;
                if (DINP == DINR || k < DINR){
                    #pragma unroll
                    for (int i = 0; i < D4; ++i){
                        int d = lane*D4 + i;
                        hm[i] += as[ks]     *Wfc[k*3*D + d]
                               + as[KS+ks]  *Wfc[k*3*D + D + d]
                               + as[2*KS+ks]*Wfc[k*3*D + 2*D + d]
                               + hs[ks]     *Wr2[k*D + d];
                    }
                }
            }
        }
        if (alive){
            #pragma unroll
            for (int i = 0; i < D4; ++i)
                hmean_o[(size_t)n*D + lane*D4 + i] = hm[i];
            #pragma unroll
            for (int w = 0; w < D4/2; ++w){
                __half2 hh = __floats2half2_rn(hm[2*w], hm[2*w+1]);
                ntab_next[(size_t)n*(D/2) + lane*(D4/2) + w] = *(u32*)&hh;
            }
        }
        float p0 = 0.f, p1 = 0.f, p2 = 0.f;
        #pragma unroll
        for (int i = 0; i < D4; ++i){
            int d = lane*D4 + i;
            p0 += rnext[0*D + d]*hm[i];
            p1 += rnext[1*D + d]*hm[i];
            p2 += rnext[2*D + d]*hm[i];
        }
        p0 += __shfl_xor(p0,1); p0 += __shfl_xor(p0,2);
        p1 += __shfl_xor(p1,1); p1 += __shfl_xor(p1,2);
        p2 += __shfl_xor(p2,1); p2 += __shfl_xor(p2,2);
        if (alive && lane < 3){
            float v = (lane == 0) ? p0 : ((lane == 1) ? p1 : p2);
            er3_next[(size_t)n*3 + lane] = v;
        }
    }
}

// ---------------- layer-3 finalize + MLP head + global max -----------------
// One thread per node; serial head loop -> FA/FR/C0 wave-uniform -> s_load.
__global__ void __launch_bounds__(256) kFin3(
    const float* __restrict__ agg,   // [N,48] normalized aggregate
    const float* __restrict__ hres,  // [N,16]
    const float* __restrict__ FAg, const float* __restrict__ FRg,
    const float* __restrict__ C0g,
    const float* __restrict__ L1b_w, const float* __restrict__ L1b_b,
    const float* __restrict__ L1c_w, const float* __restrict__ L1c_b,
    const float* __restrict__ L2_w, const float* __restrict__ L2_b,
    float* __restrict__ out)
{
    const int tid = threadIdx.x;
    const int n = blockIdx.x*256 + tid;
    float y = -INFINITY;
    if (n < NN){
        float hr[16];
        const float4* hr4 = (const float4*)(hres + (size_t)n*16);
        #pragma unroll
        for (int w = 0; w < 4; ++w){
            float4 v = hr4[w];
            hr[4*w]=v.x; hr[4*w+1]=v.y; hr[4*w+2]=v.z; hr[4*w+3]=v.w;
        }
        float acc = L2_b[0];
        for (int hd = 0; hd < 3; ++hd){
            float ag[16];
            const float4* ag4 = (const float4*)(agg + (size_t)n*48 + hd*16);
            #pragma unroll
            for (int w = 0; w < 4; ++w){
                float4 v = ag4[w];
                ag[4*w]=v.x; ag[4*w+1]=v.y; ag[4*w+2]=v.z; ag[4*w+3]=v.w;
            }
            float x1[16];
            #pragma unroll
            for (int i = 0; i < 16; ++i) x1[i] = C0g[hd*16 + i];
            #pragma unroll
            for (int k = 0; k < 16; ++k){
                const float a = ag[k], h = hr[k];
                const float* fap = FAg + hd*256 + k*16;
                const float* frp = FRg + hd*256 + k*16;
                #pragma unroll
                for (int i = 0; i < 16; ++i)
                    x1[i] += a*fap[i] + h*frp[i];
            }
            #pragma unroll
            for (int i = 0; i < 16; ++i) x1[i] = lrelu(x1[i], 0.01f);
            float x2[4];
            #pragma unroll
            for (int ii = 0; ii < 4; ++ii){
                float a = L1b_b[ii];
                #pragma unroll
                for (int i = 0; i < 16; ++i) a += x1[i]*L1b_w[i*4+ii];
                x2[ii] = lrelu(a, 0.01f);
            }
            float v = L1c_b[0];
            #pragma unroll
            for (int ii = 0; ii < 4; ++ii) v += x2[ii]*L1c_w[ii];
            acc += v*L2_w[hd];
        }
        y = acc;
    }
    __shared__ float red[256];
    red[tid] = y;
    __syncthreads();
    for (int o = 128; o > 0; o >>= 1){
        if (tid < o) red[tid] = fmaxf(red[tid], red[tid+o]);
        __syncthreads();
    }
    if (tid == 0) atomicMaxF(out, red[0]);
}

extern "C" void kernel_launch(void* const* d_in, const int* in_sizes, int n_in,
                              void* d_out, int out_size, void* d_ws, size_t ws_size,
                              hipStream_t stream) {
    const float* nf  = (const float*)d_in[0];
    const float* ef  = (const float*)d_in[1];
    const float* W1  = (const float*)d_in[2];
    const float* We1 = (const float*)d_in[3];
    const float* al1 = (const float*)d_in[4];
    const float* ar1 = (const float*)d_in[5];
    const float* ae1 = (const float*)d_in[6];
    const float* Wr1 = (const float*)d_in[7];
    const float* b1  = (const float*)d_in[8];
    const float* W2  = (const float*)d_in[9];
    const float* We2 = (const float*)d_in[10];
    const float* al2 = (const float*)d_in[11];
    const float* ar2 = (const float*)d_in[12];
    const float* ae2 = (const float*)d_in[13];
    const float* Wr2 = (const float*)d_in[14];
    const float* b2  = (const float*)d_in[15];
    const float* W3  = (const float*)d_in[16];
    const float* We3 = (const float*)d_in[17];
    const float* al3 = (const float*)d_in[18];
    const float* ar3 = (const float*)d_in[19];
    const float* ae3 = (const float*)d_in[20];
    const float* Wr3 = (const float*)d_in[21];
    const float* b3  = (const float*)d_in[22];
    const float* L1a_w = (const float*)d_in[23];
    const float* L1a_b = (const float*)d_in[24];
    const float* L1b_w = (const float*)d_in[25];
    const float* L1b_b = (const float*)d_in[26];
    const float* L1c_w = (const float*)d_in[27];
    const float* L1c_b = (const float*)d_in[28];
    const float* L2_w  = (const float*)d_in[29];
    const float* L2_b  = (const float*)d_in[30];
    const int* src = (const int*)d_in[31];
    const int* dst = (const int*)d_in[32];
    float* out = (float*)d_out;

    // ---- workspace layout ----
    float* ws = (float*)d_ws;
    u32* ntab1 = (u32*)ws;                       // [N,4] u32 (8 halves)
    u32* ntab2 = ntab1 + (size_t)NN*4;           // [N,4]
    u32* ntab3 = ntab2 + (size_t)NN*4;           // [N,8]
    float* f   = (float*)(ntab3 + (size_t)NN*8);
    float* hm2  = f;  f += (size_t)NN*8;         // layer-2 residual input f32
    float* hm3  = f;  f += (size_t)NN*16;        // layer-3 residual input f32
    float* aggb = f;  f += (size_t)NN*48;        // layer-3 normalized aggregate
    float* er3a = f;  f += (size_t)NN*3;
    float* er3b = f;  f += (size_t)NN*3;
    float* coef = f;  f += 512;
    float* FAb = f;  f += 768;
    float* FRb = f;  f += 768;
    float* C0b = f;  f += 64;
    int* deg  = (int*)f;                         // [N] (+1: ovfc)
    int* ovfc = deg + NN;                        // [1]
    int4* ovf = (int4*)(ovfc + 4);               // [4096]
    u32* pack = (u32*)(ovf + 4096);              // [N*CAPS] u32 records

    const int gSP = GXS + 4 + (NN + 255)/256;    // scatter(1280) + coef(4) + prep1(391)
    const int gN  = (NN + 255)/256;              // one thread per node
    const int gT  = (NN*4 + 255)/256;            // 4 lanes per node -> 1563

    // ---- init via DMA memset (deg + ovfc) ----
    hipMemsetAsync(deg, 0, (NN + 4)*sizeof(int), stream);

    // ---- merged scatter + coefficients + layer-1 node table + out init ----
    kScatPrep<<<gSP,256,0,stream>>>(src, dst, ef, deg, pack, ovfc, ovf,
                                    W1, al1, ar1, We1, ae1, Wr1, b1,
                                    W2, al2, ar2, We2, ae2, Wr2, b2,
                                    W3, al3, ar3, We3, ae3, Wr3, b3,
                                    L1a_w, L1a_b, coef, FAb, FRb, C0b,
                                    nf, ntab1, er3a, out);

    // ---- Layer 1: DINP=8(pad 6), DINR=6, D=8 ----
    kNode<8,6,8,false><<<gT,256,0,stream>>>(deg, pack, ovfc, ovf, ntab1, er3a,
        coef+0, coef+48, nf, W1, coef+52, coef+100,
        hm2, ntab2, er3b, coef+132, nullptr);

    // ---- Layer 2: DINP=8, DINR=8, D=16 ----
    kNode<8,8,16,false><<<gT,256,0,stream>>>(deg, pack, ovfc, ovf, ntab2, er3b,
        coef+108, coef+156, hm2, W2, coef+160, coef+288,
        hm3, ntab3, er3a, coef+352, nullptr);

    // ---- Layer 3 (AGG): DINP=16, DINR=16, D=32 -> agg[N,48] ----
    kNode<16,16,32,true><<<gT,256,0,stream>>>(deg, pack, ovfc, ovf, ntab3, er3a,
        coef+304, coef+400, hm3, W3, nullptr, nullptr,
        nullptr, nullptr, nullptr, nullptr, aggb);

    // ---- layer-3 finalize + MLP head + global max (scalar-weight) ----
    kFin3<<<gN,256,0,stream>>>(aggb, hm3, FAb, FRb, C0b,
        L1b_w, L1b_b, L1c_w, L1c_b, L2_w, L2_b, out);
}